// Round 1
// baseline (8441.425 us; speedup 1.0000x reference)
//
#include <hip/hip_runtime.h>
#include <stdint.h>
#include <math.h>

// Seq2seq LSTM, round-4 design.
// rnn_kernel: 128 WGs x 512 threads (1 WG/CU on 128 CUs, 2 waves/SIMD for TLP).
// Each WG owns 8 hidden units; wave w <-> unit (wg*8+w); each thread holds the
// 4 gate rows (i,f,g,o) of its unit restricted to its 24-element chunk in
// registers (96 fp32 VGPRs), reads each LDS vec chunk ONCE and reuses it 4x.
// h exchange: packed 4KB/slot dword array in LLC (4-slot rotation, sentinel
// 0x7F7F7F7F). Publishes are per-unit dword stores by each wave's lane 0
// (de-skewed, no cross-wave collect). Pollers (tid<256) read 16B contiguous
// each -> coalesced LLC transactions (~4-8x fewer spin requests than the old
// per-WG-64B-line scheme). Slot-reuse protocol unchanged from the verified
// design: clear own dword in slot (t+2)&3 after the gather barrier, drain via
// vmcnt(0) before the same thread's publish of h_{t+1} into that slot's
// predecessor -- transitive-gather proof makes both hazards impossible.
//
// ws: [0]      hbuf: 4 slots x 1024 dwords = 16 KB (memset 0x7F)
//     [65536]  Adec: T x 1024 bf16 decoder hidden states (1 MB)

typedef __attribute__((ext_vector_type(8))) short short8;
typedef __attribute__((ext_vector_type(4))) float f32x4;
typedef unsigned long long u64;

#define HD 1024
#define ED 512
#define TPB 256          // out_gemm / softmax block size
#define RNN_TPB 512
#define RNN_NWG 128
#define UPW 8            // hidden units per WG
#define SENT32 0x7F7F7F7Fu

#define AGT __HIP_MEMORY_SCOPE_AGENT
#define RLX __ATOMIC_RELAXED

__device__ __forceinline__ unsigned short f2bf(float f) {
  union { float f; unsigned u; } x; x.f = f;
  unsigned u = x.u;
  u += 0x7fffu + ((u >> 16) & 1u);        // RNE
  return (unsigned short)(u >> 16);
}
__device__ __forceinline__ float frcp(float x) { return __builtin_amdgcn_rcpf(x); }
__device__ __forceinline__ float fsig(float x) { return frcp(1.0f + __expf(-x)); }
__device__ __forceinline__ float ftanh(float x) { return 1.0f - 2.0f * frcp(1.0f + __expf(2.0f * x)); }

__global__ __launch_bounds__(RNN_TPB)
void rnn_kernel(const int* __restrict__ state,
                const float* __restrict__ emb,
                const float* __restrict__ encWih,
                const float* __restrict__ encWhh,
                const float* __restrict__ encbih,
                const float* __restrict__ encbhh,
                const float* __restrict__ decWhh,
                const float* __restrict__ decbih,
                const float* __restrict__ decbhh,
                unsigned int* __restrict__ hbuf,   // [4][1024] dwords (float payload)
                unsigned short* __restrict__ Adec, // [T][1024] bf16
                int S, int T) {
  __shared__ __align__(16) float vec[HD + ED];     // [h(1024) | x(512)]

  const int tid = threadIdx.x;
  const int wg  = blockIdx.x;
  const int w   = tid >> 6;          // wave id == local unit 0..7
  const int c   = tid & 63;          // lane
  const int u   = wg * UPW + w;      // global hidden unit 0..1023

  // ---- weights in registers: 4 gate rows x (4 h-chunks + 2 x-chunks) ----
  float4 wh[4][4];
  float4 wx[4][2];
  float4 br;
#pragma unroll
  for (int g = 0; g < 4; ++g) {
    const size_t rb = (size_t)(g * HD + u);
#pragma unroll
    for (int j = 0; j < 4; ++j)
      wh[g][j] = *(const float4*)&encWhh[rb * HD + 4 * (c + 64 * j)];
#pragma unroll
    for (int j = 0; j < 2; ++j)
      wx[g][j] = *(const float4*)&encWih[rb * ED + 4 * (c + 64 * j)];
  }
  br.x = encbih[0 * HD + u] + encbhh[0 * HD + u];
  br.y = encbih[1 * HD + u] + encbhh[1 * HD + u];
  br.z = encbih[2 * HD + u] + encbhh[2 * HD + u];
  br.w = encbih[3 * HD + u] + encbhh[3 * HD + u];

  // depth-1 emb prefetch register (threads 256..383 only)
  float4 xreg;
  if (tid >= 256 && tid < 384) {
    int tok = state[0];
    xreg = *(const float4*)&emb[(size_t)tok * ED + 4 * (tid - 256)];
  }

  float cs = 0.0f;                   // cell state (replicated across lanes)

  for (int t = 0; t < S + T; ++t) {
    const bool dec = (t >= S);
    if (t == S) {                    // one-time decoder weight switch
#pragma unroll
      for (int g = 0; g < 4; ++g) {
        const size_t rb = (size_t)(g * HD + u);
#pragma unroll
        for (int j = 0; j < 4; ++j)
          wh[g][j] = *(const float4*)&decWhh[rb * HD + 4 * (c + 64 * j)];
      }
      br.x = decbih[0 * HD + u] + decbhh[0 * HD + u];
      br.y = decbih[1 * HD + u] + decbhh[1 * HD + u];
      br.z = decbih[2 * HD + u] + decbhh[2 * HD + u];
      br.w = decbih[3 * HD + u] + decbhh[3 * HD + u];
    }

    // ---- gather: pollers (tid<256) pull 16B each; waves 4-5 stage x ----
    if (tid < 256) {
      if (t == 0) {
        *(float4*)&vec[4 * tid] = make_float4(0.f, 0.f, 0.f, 0.f);
      } else {
        const u64* L = (const u64*)hbuf + (((size_t)(t & 3)) << 9) + tid * 2;
        u64 d0, d1;
        do {
          d0 = __hip_atomic_load(&L[0], RLX, AGT);
          d1 = __hip_atomic_load(&L[1], RLX, AGT);
        } while ((unsigned)d0 == SENT32 || (unsigned)(d0 >> 32) == SENT32 ||
                 (unsigned)d1 == SENT32 || (unsigned)(d1 >> 32) == SENT32);
        union { u64 u[2]; float4 f; } p;
        p.u[0] = d0; p.u[1] = d1;
        *(float4*)&vec[4 * tid] = p.f;
      }
    } else if (tid < 384) {
      if (!dec) {
        *(float4*)&vec[HD + 4 * (tid - 256)] = xreg;   // x_t (prefetched)
        if (t + 1 < S) {
          int tok = state[t + 1];
          xreg = *(const float4*)&emb[(size_t)tok * ED + 4 * (tid - 256)];
        }
      }
    }
    __syncthreads();

    // ---- re-sentinel own unit's dword in slot (t+2)&3 (post-gather: every
    // WG is past step t-2, so nobody still reads h_{t-2}; drained by the
    // vmcnt(0) in THIS thread's publish below, which gates everyone's h_{t+2})
    if (c == 0)
      __hip_atomic_store(&hbuf[(size_t)((t + 2) & 3) * HD + u], SENT32, RLX, AGT);

    // ---- dot: 4 gate rows share each vec chunk (LDS traffic /4) ----
    float a0 = 0.f, a1 = 0.f, a2 = 0.f, a3 = 0.f;
#pragma unroll
    for (int j = 0; j < 4; ++j) {
      float4 v = *(const float4*)&vec[4 * (c + 64 * j)];
      a0 = fmaf(wh[0][j].x, v.x, fmaf(wh[0][j].y, v.y, fmaf(wh[0][j].z, v.z, fmaf(wh[0][j].w, v.w, a0))));
      a1 = fmaf(wh[1][j].x, v.x, fmaf(wh[1][j].y, v.y, fmaf(wh[1][j].z, v.z, fmaf(wh[1][j].w, v.w, a1))));
      a2 = fmaf(wh[2][j].x, v.x, fmaf(wh[2][j].y, v.y, fmaf(wh[2][j].z, v.z, fmaf(wh[2][j].w, v.w, a2))));
      a3 = fmaf(wh[3][j].x, v.x, fmaf(wh[3][j].y, v.y, fmaf(wh[3][j].z, v.z, fmaf(wh[3][j].w, v.w, a3))));
    }
    if (!dec) {
#pragma unroll
      for (int j = 0; j < 2; ++j) {
        float4 v = *(const float4*)&vec[HD + 4 * (c + 64 * j)];
        a0 = fmaf(wx[0][j].x, v.x, fmaf(wx[0][j].y, v.y, fmaf(wx[0][j].z, v.z, fmaf(wx[0][j].w, v.w, a0))));
        a1 = fmaf(wx[1][j].x, v.x, fmaf(wx[1][j].y, v.y, fmaf(wx[1][j].z, v.z, fmaf(wx[1][j].w, v.w, a1))));
        a2 = fmaf(wx[2][j].x, v.x, fmaf(wx[2][j].y, v.y, fmaf(wx[2][j].z, v.z, fmaf(wx[2][j].w, v.w, a2))));
        a3 = fmaf(wx[3][j].x, v.x, fmaf(wx[3][j].y, v.y, fmaf(wx[3][j].z, v.z, fmaf(wx[3][j].w, v.w, a3))));
      }
    }
    // in-wave butterfly reduce (all lanes end with full sums)
#pragma unroll
    for (int off = 1; off < 64; off <<= 1) {
      a0 += __shfl_xor(a0, off);
      a1 += __shfl_xor(a1, off);
      a2 += __shfl_xor(a2, off);
      a3 += __shfl_xor(a3, off);
    }

    // ---- LSTM cell, replicated across the wave (no divergence) ----
    float iv = fsig(a0 + br.x);
    float fv = fsig(a1 + br.y);
    float gv = ftanh(a2 + br.z);
    float ov = fsig(a3 + br.w);
    cs = fv * cs + iv * gv;
    float hv = ov * ftanh(cs);

    if (c == 0) {
      // drain the sentinel-clear (and all wave vmem) before publishing
      asm volatile("s_waitcnt vmcnt(0)" ::: "memory");
      union { float f; unsigned u; } x; x.f = hv;
      __hip_atomic_store(&hbuf[(size_t)((t + 1) & 3) * HD + u], x.u, RLX, AGT);
      if (dec) Adec[(size_t)(t - S) * HD + u] = f2bf(hv);
    }
    __syncthreads();   // vec reads done before next iteration's writes
  }
}

// ---- output head GEMM: out[t][v] = Adec[t] . Wout[v] + bout[v] ----
// WG tile: 512 t x 64 v. Wave w: t in [w*128, w*128+128), v in [v0, v0+64).
// Per k-step (K=32): stage A-slice (512x32 bf16, padded stride) in LDS,
// 8 a-frags + 4 b-frags -> 32 MFMA per wave. Wout (206 MB) read exactly once.
#define AST 56   // Alds row stride in ushorts

__global__ __launch_bounds__(TPB)
void out_gemm(const unsigned short* __restrict__ Adec,
              const float* __restrict__ Wout,
              const float* __restrict__ bout,
              float* __restrict__ out,
              int V) {
  __shared__ __align__(16) unsigned short Alds[512 * AST]; // 56 KB
  const int tid  = threadIdx.x;
  const int wv   = tid >> 6;
  const int lane = tid & 63;
  const int col  = lane & 15;
  const int quad = lane >> 4;
  const int v0   = blockIdx.x * 64;

  f32x4 acc[4][8];
#pragma unroll
  for (int bt = 0; bt < 4; ++bt)
#pragma unroll
    for (int tt = 0; tt < 8; ++tt)
      acc[bt][tt] = (f32x4){0.f, 0.f, 0.f, 0.f};

  for (int k0 = 0; k0 < HD; k0 += 32) {
    __syncthreads();
    // stage A k-slice: 512 rows x 32 bf16 (4 x uint4 chunks per row)
#pragma unroll
    for (int i = 0; i < 8; ++i) {
      int id = tid + (i << 8);             // 0..2047
      int rt = id >> 2, c4 = id & 3;
      uint4 d = *(const uint4*)(Adec + rt * HD + k0 + (c4 << 3));
      *(uint4*)&Alds[rt * AST + (c4 << 3)] = d;
    }
    __syncthreads();
    // B fragments from global (fp32 -> bf16): lane l covers Wout[v0+bt*16+col][k0+quad*8 ..+7]
    short8 bf[4];
#pragma unroll
    for (int bt = 0; bt < 4; ++bt) {
      int v = v0 + (bt << 4) + col;
      if (v >= V) v = V - 1;
      const float4* wp = (const float4*)(Wout + (size_t)v * HD + k0 + (quad << 3));
      float4 w0 = wp[0], w1 = wp[1];
      short8 b;
      b[0] = (short)f2bf(w0.x); b[1] = (short)f2bf(w0.y);
      b[2] = (short)f2bf(w0.z); b[3] = (short)f2bf(w0.w);
      b[4] = (short)f2bf(w1.x); b[5] = (short)f2bf(w1.y);
      b[6] = (short)f2bf(w1.z); b[7] = (short)f2bf(w1.w);
      bf[bt] = b;
    }
#pragma unroll
    for (int tt = 0; tt < 8; ++tt) {
      int trow = (wv << 7) + (tt << 4) + col;
      short8 af = *(const short8*)&Alds[trow * AST + (quad << 3)];
#pragma unroll
      for (int bt = 0; bt < 4; ++bt)
        acc[bt][tt] = __builtin_amdgcn_mfma_f32_16x16x32_bf16(af, bf[bt], acc[bt][tt], 0, 0, 0);
    }
  }
  // epilogue: C/D layout col = lane&15 (v), row = quad*4 + reg (t)
#pragma unroll
  for (int bt = 0; bt < 4; ++bt) {
    int v = v0 + (bt << 4) + col;
    if (v < V) {
      float bb = bout[v];
#pragma unroll
      for (int tt = 0; tt < 8; ++tt) {
        int tb = (wv << 7) + (tt << 4) + (quad << 2);
        f32x4 a = acc[bt][tt];
        out[(size_t)(tb + 0) * V + v] = a[0] + bb;
        out[(size_t)(tb + 1) * V + v] = a[1] + bb;
        out[(size_t)(tb + 2) * V + v] = a[2] + bb;
        out[(size_t)(tb + 3) * V + v] = a[3] + bb;
      }
    }
  }
}

// ---- row softmax in place over d_out: one WG per t ----
__global__ __launch_bounds__(TPB)
void softmax_rows(float* __restrict__ out, int V) {
  float* rowp = out + (size_t)blockIdx.x * V;
  __shared__ float red[8];
  const int tid = threadIdx.x;

  float m = -1e30f;
  for (int v = tid; v < V; v += TPB) m = fmaxf(m, rowp[v]);
#pragma unroll
  for (int off = 32; off >= 1; off >>= 1) m = fmaxf(m, __shfl_xor(m, off));
  if ((tid & 63) == 0) red[tid >> 6] = m;
  __syncthreads();
  if (tid == 0) red[4] = fmaxf(fmaxf(red[0], red[1]), fmaxf(red[2], red[3]));
  __syncthreads();
  m = red[4];

  float s = 0.0f;
  for (int v = tid; v < V; v += TPB) {
    float e = expf(rowp[v] - m);
    rowp[v] = e;
    s += e;
  }
#pragma unroll
  for (int off = 32; off >= 1; off >>= 1) s += __shfl_xor(s, off);
  if ((tid & 63) == 0) red[tid >> 6] = s;
  __syncthreads();
  if (tid == 0) red[5] = red[0] + red[1] + red[2] + red[3];
  __syncthreads();
  float inv = 1.0f / red[5];
  for (int v = tid; v < V; v += TPB) rowp[v] *= inv;
}

extern "C" void kernel_launch(void* const* d_in, const int* in_sizes, int n_in,
                              void* d_out, int out_size, void* d_ws, size_t ws_size,
                              hipStream_t stream) {
  const int*   state  = (const int*)d_in[0];
  // d_in[1] = max_len scalar (T derived from out_size instead)
  const float* emb    = (const float*)d_in[2];
  const float* encWih = (const float*)d_in[3];
  const float* encWhh = (const float*)d_in[4];
  const float* encbih = (const float*)d_in[5];
  const float* encbhh = (const float*)d_in[6];
  // d_in[7] = dec_Wih (multiplied by zero input in reference -> unused)
  const float* decWhh = (const float*)d_in[8];
  const float* decbih = (const float*)d_in[9];
  const float* decbhh = (const float*)d_in[10];
  const float* Wout   = (const float*)d_in[11];
  const float* bout   = (const float*)d_in[12];
  float*       out    = (float*)d_out;

  const int S = in_sizes[0];          // 2048
  const int V = in_sizes[12];         // 50257
  const int T = out_size / V;         // 512

  // sentinel-fill the packed h slots (0x7F byte pattern)
  hipMemsetAsync(d_ws, 0x7F, 16384, stream);
  unsigned int*   hbuf = (unsigned int*)d_ws;
  unsigned short* Adec = (unsigned short*)((char*)d_ws + 65536);

  rnn_kernel<<<RNN_NWG, RNN_TPB, 0, stream>>>(state, emb, encWih, encWhh, encbih, encbhh,
                                              decWhh, decbih, decbhh, hbuf, Adec, S, T);
  int nvb = (V + 63) / 64;
  out_gemm<<<nvb, TPB, 0, stream>>>(Adec, Wout, bout, out, V);
  softmax_rows<<<T, TPB, 0, stream>>>(out, V);
}